// Round 12
// baseline (197.206 us; speedup 1.0000x reference)
//
#include <hip/hip_runtime.h>
#include <hip/hip_bf16.h>

#define B_ROWS 4096
#define D_DIM  512
#define N_ROWS 8192   // 2B
#define BM 64
#define BN 64
#define BKB 128       // K-tile in BYTES (= fp8 elements); row stride 128B, 8x16B granules
#define NBLK (N_ROWS / BM)             // 128 row-blocks
#define NPAIR (NBLK * (NBLK + 1) / 2)  // 8256 upper-tri block pairs

typedef float f32x4 __attribute__((ext_vector_type(4)));
typedef int   v4i   __attribute__((ext_vector_type(4)));
typedef int   v8i   __attribute__((ext_vector_type(8)));

// 16-lane row reduction entirely on the VALU pipe (DPP), zero DS ops.
__device__ __forceinline__ float dpp_xor1_add(float v) {
    return v + __int_as_float(__builtin_amdgcn_mov_dpp(
        __float_as_int(v), 0xB1, 0xf, 0xf, true));   // quad_perm [1,0,3,2]
}
__device__ __forceinline__ float dpp_xor2_add(float v) {
    return v + __int_as_float(__builtin_amdgcn_mov_dpp(
        __float_as_int(v), 0x4E, 0xf, 0xf, true));   // quad_perm [2,3,0,1]
}
__device__ __forceinline__ float dpp_ror4_add(float v) {
    return v + __int_as_float(__builtin_amdgcn_mov_dpp(
        __float_as_int(v), 0x124, 0xf, 0xf, true));  // row_ror:4
}
__device__ __forceinline__ float dpp_ror8_add(float v) {
    return v + __int_as_float(__builtin_amdgcn_mov_dpp(
        __float_as_int(v), 0x128, 0xf, 0xf, true));  // row_ror:8
}

// ---------------------------------------------------------------------------
// Kernel 1: prep, one WAVE per row-pair r (no LDS, no barriers). Verified r7.
// ---------------------------------------------------------------------------
__global__ __launch_bounds__(256) void prep_kernel(
    const float* __restrict__ poly, const float* __restrict__ cemb,
    unsigned char* __restrict__ Z, float* __restrict__ row_sum,
    float* __restrict__ pos, unsigned int* __restrict__ counter)
{
    const int wave = threadIdx.x >> 6;
    const int lane = threadIdx.x & 63;
    const int r = blockIdx.x * 4 + wave;          // 1024 blocks x 4 waves

    const float4* prow = (const float4*)(poly + (size_t)r * D_DIM) + lane * 2;
    const float4* crow = (const float4*)(cemb + (size_t)r * D_DIM) + lane * 2;
    const float4 p0 = prow[0], p1 = prow[1];
    const float4 c0 = crow[0], c1 = crow[1];

    float ssp = p0.x*p0.x + p0.y*p0.y + p0.z*p0.z + p0.w*p0.w
              + p1.x*p1.x + p1.y*p1.y + p1.z*p1.z + p1.w*p1.w;
    float ssc = c0.x*c0.x + c0.y*c0.y + c0.z*c0.z + c0.w*c0.w
              + c1.x*c1.x + c1.y*c1.y + c1.z*c1.z + c1.w*c1.w;
    float dt  = p0.x*c0.x + p0.y*c0.y + p0.z*c0.z + p0.w*c0.w
              + p1.x*c1.x + p1.y*c1.y + p1.z*c1.z + p1.w*c1.w;

    #pragma unroll
    for (int m = 1; m < 64; m <<= 1) {
        ssp += __shfl_xor(ssp, m);
        ssc += __shfl_xor(ssc, m);
        dt  += __shfl_xor(dt,  m);
    }

    const float sp = 1.0f / fmaxf(sqrtf(ssp), 1e-12f);
    const float sc = 1.0f / fmaxf(sqrtf(ssc), 1e-12f);

    int2 zp, zc;
    zp.x = __builtin_amdgcn_cvt_pk_fp8_f32(p0.x*sp, p0.y*sp, 0, false)
         | (__builtin_amdgcn_cvt_pk_fp8_f32(p0.z*sp, p0.w*sp, 0, false) << 16);
    zp.y = __builtin_amdgcn_cvt_pk_fp8_f32(p1.x*sp, p1.y*sp, 0, false)
         | (__builtin_amdgcn_cvt_pk_fp8_f32(p1.z*sp, p1.w*sp, 0, false) << 16);
    zc.x = __builtin_amdgcn_cvt_pk_fp8_f32(c0.x*sc, c0.y*sc, 0, false)
         | (__builtin_amdgcn_cvt_pk_fp8_f32(c0.z*sc, c0.w*sc, 0, false) << 16);
    zc.y = __builtin_amdgcn_cvt_pk_fp8_f32(c1.x*sc, c1.y*sc, 0, false)
         | (__builtin_amdgcn_cvt_pk_fp8_f32(c1.z*sc, c1.w*sc, 0, false) << 16);

    *(int2*)(Z + (size_t)r * D_DIM + lane * 8)            = zp;
    *(int2*)(Z + (size_t)(r + B_ROWS) * D_DIM + lane * 8) = zc;

    if (lane == 0) {
        pos[r] = dt * sp * sc;
        row_sum[2 * r]     = 0.0f;
        row_sum[2 * r + 1] = 0.0f;
        if (r == 0) *counter = 0u;
    }
}

// ---------------------------------------------------------------------------
// Kernel 2: symmetric sim = Z Z^T via mfma_scale_f32_16x16x128_f8f6f4 with
// UNIT scales (verified absmax 0.0 in rounds 1-11).
//
// Rounds 7-11: every pipe-throughput lever is null (MFMA rate 2x, DS volume
// -33%, barriers 8->5->0, epilogue DS -40%); time pinned at ~60 us with NO
// pipe >30% busy => latency-bound on independent work streams. r7 had only
// TWO independent 8-wave barrier domains/CU and a ~12% grid tail (2080 =
// 8x256+32).
//
// This round: same per-WAVE profile as r7 (64x32 tile, acc[4][2], 12 b128 +
// 8 MFMA per K-step, identical swizzle formulas) repackaged as BM=BN=64,
// 2-WAVE blocks: NPAIR = 8256 (32.25/CU, tail ~3%), 17 KB LDS -> 8-9
// independent blocks/CU (4x r7's barrier-domain count). Staging traffic
// doubles (all L2 hits, DMA-overlapped) -- accepted price.
// Epilogue: r10's verified VALU-DPP row reduce + race-free ds_write slots
// (rP[64][2] by wave; cP[64] wave-disjoint cols). Natural allocation, NO
// min-waves cap (r2/r3: caps => spill).
// ---------------------------------------------------------------------------
__global__ __launch_bounds__(128) void sim_kernel(
    const unsigned char* __restrict__ Z, float* __restrict__ row_sum,
    const float* __restrict__ pos, float* __restrict__ out,
    unsigned int* __restrict__ counter)
{
    __shared__ __align__(16) unsigned char As[BM * BKB];   // 8 KB
    __shared__ __align__(16) unsigned char Bs[BN * BKB];   // 8 KB
    __shared__ __align__(8)  float rP[BM][2];              // 512 B row partials
    __shared__ __align__(4)  float cP[BN];                 // 256 B col partials
    __shared__ unsigned int lastFlag;

    // decode blockIdx.x -> (bi, bj), bi <= bj < 128; C(b) = b*(257-b)/2
    const int t0 = blockIdx.x;
    int bi = (int)((257.0f - sqrtf(66049.0f - 8.0f * (float)t0)) * 0.5f);
    #define CFN(b) ((b) * (257 - (b)) / 2)
    while (CFN(bi + 1) <= t0) ++bi;
    while (CFN(bi) > t0) --bi;
    const int bj = bi + (t0 - CFN(bi));
    #undef CFN
    const bool diag = (bi == bj);

    const int ibase = bi * BM;
    const int jbase = bj * BN;
    const int tid   = threadIdx.x;

    const int srow = tid >> 3;                 // staging row (0..15) within 16-row group
    const int gchk = (tid & 7) ^ (srow & 7);   // swizzled source granule (16B)

    const int wave = tid >> 6;                 // 0..1
    const int lane = tid & 63;
    const int wj = wave * 32;                  // wave 0: cols 0-31, wave 1: 32-63
    const int quad = lane >> 4;
    const int c    = lane & 15;

    f32x4 acc[4][2] = {};

    // LDS granule G of row R holds global granule G ^ (R&7); fragment rows
    // have R&7 == c&7. Lane needs global k = quad*32 .. +32 -> granules
    // 2*quad, 2*quad+1 at swizzled slots:
    const int sg0 = (((quad << 1)    ) ^ (c & 7)) * 16;
    const int sg1 = (((quad << 1) | 1) ^ (c & 7)) * 16;

    #pragma unroll 1
    for (int k0 = 0; k0 < D_DIM; k0 += BKB) {   // 4 iterations, rolled
        #pragma unroll
        for (int it = 0; it < 4; ++it) {        // 128 thr x 16B x 4 = 8 KB
            const int row = it * 16 + srow;
            const unsigned char* ga = Z + (size_t)(ibase + row) * D_DIM + k0 + gchk * 16;
            __builtin_amdgcn_global_load_lds(
                (const __attribute__((address_space(1))) void*)ga,
                (__attribute__((address_space(3))) void*)(As + it * 2048 + tid * 16),
                16, 0, 0);
        }
        if (!diag) {
            #pragma unroll
            for (int it = 0; it < 4; ++it) {
                const int row = it * 16 + srow;
                const unsigned char* gb = Z + (size_t)(jbase + row) * D_DIM + k0 + gchk * 16;
                __builtin_amdgcn_global_load_lds(
                    (const __attribute__((address_space(1))) void*)gb,
                    (__attribute__((address_space(3))) void*)(Bs + it * 2048 + tid * 16),
                    16, 0, 0);
            }
        }
        __syncthreads();

        const unsigned char* bb = diag ? As : Bs;

        v8i bfr[2];
        #pragma unroll
        for (int tj = 0; tj < 2; ++tj) {
            const unsigned char* base = bb + (wj + tj * 16 + c) * BKB;
            const v4i lo = *(const v4i*)(base + sg0);
            const v4i hi = *(const v4i*)(base + sg1);
            bfr[tj] = __builtin_shufflevector(lo, hi, 0, 1, 2, 3, 4, 5, 6, 7);
        }
        #pragma unroll
        for (int ti = 0; ti < 4; ++ti) {
            const unsigned char* base = As + (ti * 16 + c) * BKB;
            const v4i lo = *(const v4i*)(base + sg0);
            const v4i hi = *(const v4i*)(base + sg1);
            const v8i afr = __builtin_shufflevector(lo, hi, 0, 1, 2, 3, 4, 5, 6, 7);
            #pragma unroll
            for (int tj = 0; tj < 2; ++tj)
                acc[ti][tj] = __builtin_amdgcn_mfma_scale_f32_16x16x128_f8f6f4(
                    afr, bfr[tj], acc[ti][tj],
                    0, 0,                 // cbsz / blgp: fp8 e4m3 both
                    0, 0x7f7f7f7f,        // opsel_a, scale_a = 1.0 (E8M0 127)
                    0, 0x7f7f7f7f);       // opsel_b, scale_b = 1.0
        }
        __syncthreads();
    }

    // ---- Epilogue: exp(sim/T); row/col sums via VALU-DPP + plain writes ----
    const float K2 = 2.885390081777927f;  // 2*log2(e) = 1/(T*ln2)
    float col[2] = {0.0f, 0.0f};

    #pragma unroll
    for (int ti = 0; ti < 4; ++ti) {
        const int li = ti * 16 + quad * 4;
        #pragma unroll
        for (int r = 0; r < 4; ++r) {
            float v = 0.0f;
            if (diag) {                    // wave-uniform branch (128/8256 blocks)
                const int gi = ibase + li + r;
                #pragma unroll
                for (int tj = 0; tj < 2; ++tj) {
                    const int gj = jbase + wj + tj * 16 + c;
                    const float e = (gj > gi) ? exp2f(K2 * acc[ti][tj][r]) : 0.0f;
                    v += e;
                    col[tj] += e;
                }
            } else {                       // 98.4% of blocks: no predicate
                #pragma unroll
                for (int tj = 0; tj < 2; ++tj) {
                    const float e = exp2f(K2 * acc[ti][tj][r]);
                    v += e;
                    col[tj] += e;
                }
            }
            v = dpp_xor1_add(v);           // 16-lane row sum: pure VALU
            v = dpp_xor2_add(v);
            v = dpp_ror4_add(v);
            v = dpp_ror8_add(v);
            if (c == 0)
                rP[li + r][wave] = v;      // plain write, race-free slot
        }
    }
    #pragma unroll
    for (int tj = 0; tj < 2; ++tj) {
        float w = col[tj];
        w += __shfl_xor(w, 16);
        w += __shfl_xor(w, 32);
        if (quad == 0)
            cP[wj + tj * 16 + c] = w;      // plain write, wave-disjoint cols
    }
    __syncthreads();

    if (tid < BM) {
        const float2 rp = *(const float2*)rP[tid];
        atomicAdd(&row_sum[ibase + tid], rp.x + rp.y);
    } else {
        atomicAdd(&row_sum[jbase + tid - BM], cP[tid - BM]);
    }

    // ---- Completion count; last block computes the loss (fence-free) ----
    __syncthreads();   // barrier implies vmcnt(0): this block's atomics issued
    if (tid == 0) {
        unsigned int old = __hip_atomic_fetch_add(
            counter, 1u, __ATOMIC_RELAXED, __HIP_MEMORY_SCOPE_AGENT);
        lastFlag = (old == NPAIR - 1) ? 1u : 0u;
    }
    __syncthreads();
    if (lastFlag) {
        float accL = 0.0f, accP = 0.0f;
        for (int i = tid; i < N_ROWS; i += 128) {
            const float rs = __hip_atomic_load(
                &row_sum[i], __ATOMIC_RELAXED, __HIP_MEMORY_SCOPE_AGENT);
            accL += __logf(rs);
        }
        for (int r = tid; r < B_ROWS; r += 128)
            accP += pos[r];
        #pragma unroll
        for (int m = 1; m < 64; m <<= 1) {
            accL += __shfl_xor(accL, m);
            accP += __shfl_xor(accP, m);
        }
        if (lane == 0) { rP[wave][0] = accL; rP[wave][1] = accP; }
        __syncthreads();
        if (tid == 0) {
            out[0] = ((rP[0][0] + rP[1][0]) - 4.0f * (rP[0][1] + rP[1][1]))
                     / (float)N_ROWS;
        }
    }
}

extern "C" void kernel_launch(void* const* d_in, const int* in_sizes, int n_in,
                              void* d_out, int out_size, void* d_ws, size_t ws_size,
                              hipStream_t stream) {
    const float* poly = (const float*)d_in[0];
    const float* cemb = (const float*)d_in[1];

    unsigned char* Z       = (unsigned char*)d_ws;
    float*         row_sum = (float*)((char*)d_ws + (size_t)N_ROWS * D_DIM);
    float*         pos     = row_sum + N_ROWS;
    unsigned int*  counter = (unsigned int*)(pos + B_ROWS);
    float*         out     = (float*)d_out;

    prep_kernel<<<B_ROWS / 4, 256, 0, stream>>>(poly, cemb, Z, row_sum, pos, counter);
    sim_kernel<<<NPAIR, 128, 0, stream>>>(Z, row_sum, pos, out, counter);
}

// Round 13
// 114.570 us; speedup vs baseline: 1.7213x; 1.7213x over previous
//
#include <hip/hip_runtime.h>
#include <hip/hip_bf16.h>

#define B_ROWS 4096
#define D_DIM  512
#define N_ROWS 8192   // 2B
#define BM 128
#define BN 128
#define BKB 128       // K-tile in BYTES (= fp8 elements); row stride 128B, 8x16B granules
#define NBLK (N_ROWS / BM)             // 64 row-blocks
#define NPAIR (NBLK * (NBLK + 1) / 2)  // 2080 upper-tri block pairs

typedef float f32x4 __attribute__((ext_vector_type(4)));
typedef int   v4i   __attribute__((ext_vector_type(4)));
typedef int   v8i   __attribute__((ext_vector_type(8)));

// 16-lane row reduction entirely on the VALU pipe (DPP), zero DS ops.
__device__ __forceinline__ float dpp_xor1_add(float v) {
    return v + __int_as_float(__builtin_amdgcn_mov_dpp(
        __float_as_int(v), 0xB1, 0xf, 0xf, true));   // quad_perm [1,0,3,2]
}
__device__ __forceinline__ float dpp_xor2_add(float v) {
    return v + __int_as_float(__builtin_amdgcn_mov_dpp(
        __float_as_int(v), 0x4E, 0xf, 0xf, true));   // quad_perm [2,3,0,1]
}
__device__ __forceinline__ float dpp_ror4_add(float v) {
    return v + __int_as_float(__builtin_amdgcn_mov_dpp(
        __float_as_int(v), 0x124, 0xf, 0xf, true));  // row_ror:4
}
__device__ __forceinline__ float dpp_ror8_add(float v) {
    return v + __int_as_float(__builtin_amdgcn_mov_dpp(
        __float_as_int(v), 0x128, 0xf, 0xf, true));  // row_ror:8
}

// ---------------------------------------------------------------------------
// Kernel 1: prep, one WAVE per row-pair r (no LDS, no barriers). Verified r7.
// ---------------------------------------------------------------------------
__global__ __launch_bounds__(256) void prep_kernel(
    const float* __restrict__ poly, const float* __restrict__ cemb,
    unsigned char* __restrict__ Z, float* __restrict__ row_sum,
    float* __restrict__ pos, unsigned int* __restrict__ counter)
{
    const int wave = threadIdx.x >> 6;
    const int lane = threadIdx.x & 63;
    const int r = blockIdx.x * 4 + wave;          // 1024 blocks x 4 waves

    const float4* prow = (const float4*)(poly + (size_t)r * D_DIM) + lane * 2;
    const float4* crow = (const float4*)(cemb + (size_t)r * D_DIM) + lane * 2;
    const float4 p0 = prow[0], p1 = prow[1];
    const float4 c0 = crow[0], c1 = crow[1];

    float ssp = p0.x*p0.x + p0.y*p0.y + p0.z*p0.z + p0.w*p0.w
              + p1.x*p1.x + p1.y*p1.y + p1.z*p1.z + p1.w*p1.w;
    float ssc = c0.x*c0.x + c0.y*c0.y + c0.z*c0.z + c0.w*c0.w
              + c1.x*c1.x + c1.y*c1.y + c1.z*c1.z + c1.w*c1.w;
    float dt  = p0.x*c0.x + p0.y*c0.y + p0.z*c0.z + p0.w*c0.w
              + p1.x*c1.x + p1.y*c1.y + p1.z*c1.z + p1.w*c1.w;

    #pragma unroll
    for (int m = 1; m < 64; m <<= 1) {
        ssp += __shfl_xor(ssp, m);
        ssc += __shfl_xor(ssc, m);
        dt  += __shfl_xor(dt,  m);
    }

    const float sp = 1.0f / fmaxf(sqrtf(ssp), 1e-12f);
    const float sc = 1.0f / fmaxf(sqrtf(ssc), 1e-12f);

    int2 zp, zc;
    zp.x = __builtin_amdgcn_cvt_pk_fp8_f32(p0.x*sp, p0.y*sp, 0, false)
         | (__builtin_amdgcn_cvt_pk_fp8_f32(p0.z*sp, p0.w*sp, 0, false) << 16);
    zp.y = __builtin_amdgcn_cvt_pk_fp8_f32(p1.x*sp, p1.y*sp, 0, false)
         | (__builtin_amdgcn_cvt_pk_fp8_f32(p1.z*sp, p1.w*sp, 0, false) << 16);
    zc.x = __builtin_amdgcn_cvt_pk_fp8_f32(c0.x*sc, c0.y*sc, 0, false)
         | (__builtin_amdgcn_cvt_pk_fp8_f32(c0.z*sc, c0.w*sc, 0, false) << 16);
    zc.y = __builtin_amdgcn_cvt_pk_fp8_f32(c1.x*sc, c1.y*sc, 0, false)
         | (__builtin_amdgcn_cvt_pk_fp8_f32(c1.z*sc, c1.w*sc, 0, false) << 16);

    *(int2*)(Z + (size_t)r * D_DIM + lane * 8)            = zp;
    *(int2*)(Z + (size_t)(r + B_ROWS) * D_DIM + lane * 8) = zc;

    if (lane == 0) {
        pos[r] = dt * sp * sc;
        row_sum[2 * r]     = 0.0f;
        row_sum[2 * r + 1] = 0.0f;
        if (r == 0) *counter = 0u;
    }
}

// ---------------------------------------------------------------------------
// Kernel 2: symmetric sim = Z Z^T via mfma_scale_f32_16x16x128_f8f6f4 with
// UNIT scales (verified absmax 0.0 in rounds 1-12).
//
// r12 falsified "more barrier domains": 4x smaller blocks = 2.3x slower
// (per-block fixed latency x blocks/CU is the law; big tiles amortize).
// Back to the r7/r8 lineage (128^2, 8 waves x 64x32/wave).
//
// The ONE untested mechanism: every staged variant used __syncthreads(),
// whose lowering DRAINS vmcnt to 0 at each barrier -- r8's dbuf prefetch
// never actually stayed in flight (the documented m97-structure stall;
// T4 counted-vmcnt is +38-73% over drain-0 in the catalog). This round:
// r8's verified dbuf control flow with RAW s_barrier + counted vmcnt:
//   iter t: issue stage(t+1) -> s_waitcnt vmcnt(4 offdiag / 2 diag)
//           [= stage(t) complete, stage(t+1) IN FLIGHT across the barrier]
//           -> s_barrier -> ds_read+MFMA(buf t&1) -> lgkmcnt(0)
//           -> s_barrier [buf t&1 safe to overwrite at t+2]
// Last iter waits vmcnt(0). Stage L2 latency hides under the 32-MFMA
// compute phase. Epilogue: r10's verified VALU-DPP + race-free slots.
// Natural allocation, NO min-waves cap (r2/r3: caps => spill).
// ---------------------------------------------------------------------------
__global__ __launch_bounds__(512) void sim_kernel(
    const unsigned char* __restrict__ Z, float* __restrict__ row_sum,
    const float* __restrict__ pos, float* __restrict__ out,
    unsigned int* __restrict__ counter)
{
    __shared__ __align__(16) unsigned char As[2][BM * BKB];   // 2 x 16 KB
    __shared__ __align__(16) unsigned char Bs[2][BN * BKB];   // 2 x 16 KB
    __shared__ __align__(16) float rP[BM][4];                 // 2 KB row partials
    __shared__ __align__(8)  float cP[BN][2];                 // 1 KB col partials
    __shared__ unsigned int lastFlag;

    // decode blockIdx.x -> (bi, bj), bi <= bj < 64; C(b) = b*(129-b)/2
    const int t0 = blockIdx.x;
    int bi = (int)((129.0f - sqrtf(16641.0f - 8.0f * (float)t0)) * 0.5f);
    #define CFN(b) ((b) * (129 - (b)) / 2)
    while (CFN(bi + 1) <= t0) ++bi;
    while (CFN(bi) > t0) --bi;
    const int bj = bi + (t0 - CFN(bi));
    #undef CFN
    const bool diag = (bi == bj);

    const int ibase = bi * BM;
    const int jbase = bj * BN;
    const int tid   = threadIdx.x;

    const int srow = tid >> 3;                 // staging row (0..63) within 64-row group
    const int gchk = (tid & 7) ^ (srow & 7);   // swizzled source granule (16B)

    const int wave = tid >> 6;                 // 0..7
    const int lane = tid & 63;
    const int wi = (wave >> 2) * 64;           // 2 row groups of 64
    const int wj = (wave & 3) * 32;            // 4 col groups of 32
    const int quad = lane >> 4;
    const int c    = lane & 15;

    f32x4 acc[4][2] = {};

    // LDS granule G of row R holds global granule G ^ (R&7); fragment rows
    // have R&7 == c&7. Lane needs global k = quad*32 .. +32 -> granules
    // 2*quad, 2*quad+1 at swizzled slots:
    const int sg0 = (((quad << 1)    ) ^ (c & 7)) * 16;
    const int sg1 = (((quad << 1) | 1) ^ (c & 7)) * 16;

    auto stage = [&](int buf, int k0) {
        #pragma unroll
        for (int it = 0; it < 2; ++it) {        // 512 thr x 16B x 2 = 16 KB
            const int row = it * 64 + srow;
            const unsigned char* ga = Z + (size_t)(ibase + row) * D_DIM + k0 + gchk * 16;
            __builtin_amdgcn_global_load_lds(
                (const __attribute__((address_space(1))) void*)ga,
                (__attribute__((address_space(3))) void*)(&As[buf][it * 8192 + tid * 16]),
                16, 0, 0);
        }
        if (!diag) {
            #pragma unroll
            for (int it = 0; it < 2; ++it) {
                const int row = it * 64 + srow;
                const unsigned char* gb = Z + (size_t)(jbase + row) * D_DIM + k0 + gchk * 16;
                __builtin_amdgcn_global_load_lds(
                    (const __attribute__((address_space(1))) void*)gb,
                    (__attribute__((address_space(3))) void*)(&Bs[buf][it * 8192 + tid * 16]),
                    16, 0, 0);
            }
        }
    };

    stage(0, 0);   // tile 0 in flight; first wait is inside the loop

    #pragma unroll 1
    for (int t = 0; t < 4; ++t) {
        if (t < 3) stage((t + 1) & 1, (t + 1) * BKB);   // prefetch stays in flight

        // Counted wait: stage(t) writes complete; stage(t+1) rides across
        // the barrier (per-wave issue counts: 4 off-diag / 2 diag).
        if (t < 3) {
            if (diag) asm volatile("s_waitcnt vmcnt(2)" ::: "memory");
            else      asm volatile("s_waitcnt vmcnt(4)" ::: "memory");
        } else {
            asm volatile("s_waitcnt vmcnt(0)" ::: "memory");
        }
        __builtin_amdgcn_s_barrier();           // all waves' stage(t) landed
        __builtin_amdgcn_sched_barrier(0);

        const unsigned char* ab = As[t & 1];
        const unsigned char* bb = diag ? ab : Bs[t & 1];

        v8i bfr[2];
        #pragma unroll
        for (int tj = 0; tj < 2; ++tj) {
            const unsigned char* base = bb + (wj + tj * 16 + c) * BKB;
            const v4i lo = *(const v4i*)(base + sg0);
            const v4i hi = *(const v4i*)(base + sg1);
            bfr[tj] = __builtin_shufflevector(lo, hi, 0, 1, 2, 3, 4, 5, 6, 7);
        }
        #pragma unroll
        for (int ti = 0; ti < 4; ++ti) {
            const unsigned char* base = ab + (wi + ti * 16 + c) * BKB;
            const v4i lo = *(const v4i*)(base + sg0);
            const v4i hi = *(const v4i*)(base + sg1);
            const v8i afr = __builtin_shufflevector(lo, hi, 0, 1, 2, 3, 4, 5, 6, 7);
            #pragma unroll
            for (int tj = 0; tj < 2; ++tj)
                acc[ti][tj] = __builtin_amdgcn_mfma_scale_f32_16x16x128_f8f6f4(
                    afr, bfr[tj], acc[ti][tj],
                    0, 0,                 // cbsz / blgp: fp8 e4m3 both
                    0, 0x7f7f7f7f,        // opsel_a, scale_a = 1.0 (E8M0 127)
                    0, 0x7f7f7f7f);       // opsel_b, scale_b = 1.0
        }

        asm volatile("s_waitcnt lgkmcnt(0)" ::: "memory");  // reads of buf t&1 done
        __builtin_amdgcn_s_barrier();           // buf t&1 safe to overwrite at t+2
    }

    // ---- Epilogue: exp(sim/T); row/col sums via VALU-DPP + plain writes ----
    const float K2 = 2.885390081777927f;  // 2*log2(e) = 1/(T*ln2)
    const int g = wave & 3;               // wj-group  -> rP slot
    const int h = wave >> 2;              // wi-half   -> cP slot
    float col[2] = {0.0f, 0.0f};

    #pragma unroll
    for (int ti = 0; ti < 4; ++ti) {
        const int li = wi + ti * 16 + quad * 4;
        #pragma unroll
        for (int r = 0; r < 4; ++r) {
            float v = 0.0f;
            if (diag) {                    // wave-uniform branch (64/2080 blocks)
                const int gi = ibase + li + r;
                #pragma unroll
                for (int tj = 0; tj < 2; ++tj) {
                    const int gj = jbase + wj + tj * 16 + c;
                    const float e = (gj > gi) ? exp2f(K2 * acc[ti][tj][r]) : 0.0f;
                    v += e;
                    col[tj] += e;
                }
            } else {                       // 97% of blocks: no predicate
                #pragma unroll
                for (int tj = 0; tj < 2; ++tj) {
                    const float e = exp2f(K2 * acc[ti][tj][r]);
                    v += e;
                    col[tj] += e;
                }
            }
            v = dpp_xor1_add(v);           // 16-lane row sum: pure VALU
            v = dpp_xor2_add(v);
            v = dpp_ror4_add(v);
            v = dpp_ror8_add(v);
            if (c == 0)
                rP[li + r][g] = v;         // plain write, race-free slot
        }
    }
    #pragma unroll
    for (int tj = 0; tj < 2; ++tj) {
        float w = col[tj];
        w += __shfl_xor(w, 16);
        w += __shfl_xor(w, 32);
        if (quad == 0)
            cP[wj + tj * 16 + c][h] = w;   // plain write, race-free slot
    }
    __syncthreads();

    if (tid < BM) {
        const float4 rp = *(const float4*)rP[tid];
        atomicAdd(&row_sum[ibase + tid], rp.x + rp.y + rp.z + rp.w);
    } else if (tid < 2 * BM) {
        const float2 cp = *(const float2*)cP[tid - BM];
        atomicAdd(&row_sum[jbase + tid - BM], cp.x + cp.y);
    }

    // ---- Completion count; last block computes the loss (fence-free) ----
    __syncthreads();   // barrier implies vmcnt(0): this block's atomics issued
    if (tid == 0) {
        unsigned int old = __hip_atomic_fetch_add(
            counter, 1u, __ATOMIC_RELAXED, __HIP_MEMORY_SCOPE_AGENT);
        lastFlag = (old == NPAIR - 1) ? 1u : 0u;
    }
    __syncthreads();
    if (lastFlag) {
        float accL = 0.0f, accP = 0.0f;
        for (int i = tid; i < N_ROWS; i += 512) {
            const float rs = __hip_atomic_load(
                &row_sum[i], __ATOMIC_RELAXED, __HIP_MEMORY_SCOPE_AGENT);
            accL += __logf(rs);
        }
        for (int r = tid; r < B_ROWS; r += 512)
            accP += pos[r];
        #pragma unroll
        for (int m = 1; m < 64; m <<= 1) {
            accL += __shfl_xor(accL, m);
            accP += __shfl_xor(accP, m);
        }
        if (lane == 0) { rP[wave][0] = accL; cP[wave][0] = accP; }
        __syncthreads();
        if (tid == 0) {
            float L = 0.0f, P = 0.0f;
            #pragma unroll
            for (int w = 0; w < 8; ++w) { L += rP[w][0]; P += cP[w][0]; }
            out[0] = (L - 4.0f * P) / (float)N_ROWS;
        }
    }
}

extern "C" void kernel_launch(void* const* d_in, const int* in_sizes, int n_in,
                              void* d_out, int out_size, void* d_ws, size_t ws_size,
                              hipStream_t stream) {
    const float* poly = (const float*)d_in[0];
    const float* cemb = (const float*)d_in[1];

    unsigned char* Z       = (unsigned char*)d_ws;
    float*         row_sum = (float*)((char*)d_ws + (size_t)N_ROWS * D_DIM);
    float*         pos     = row_sum + N_ROWS;
    unsigned int*  counter = (unsigned int*)(pos + B_ROWS);
    float*         out     = (float*)d_out;

    prep_kernel<<<B_ROWS / 4, 256, 0, stream>>>(poly, cemb, Z, row_sum, pos, counter);
    sim_kernel<<<NPAIR, 512, 0, stream>>>(Z, row_sum, pos, out, counter);
}